// Round 1
// baseline (382.871 us; speedup 1.0000x reference)
//
#include <hip/hip_runtime.h>
#include <hip/hip_bf16.h>

// ---------------- static problem constants ----------------
static constexpr int BS     = 4;
static constexpr int EMBED  = 256;
static constexpr int HEADS  = 8;
static constexpr int LEVELS = 4;
static constexpr int POINTS = 4;
static constexpr int HD     = 32;               // EMBED / HEADS
static constexpr int LQ     = 12240;            // sum of level areas
static constexpr int NROW   = BS * LQ;          // 48960 rows
static constexpr int LVL_W[4]  = {96, 48, 24, 12};
static constexpr int LVL_H[4]  = {96, 48, 24, 12};
static constexpr int LVL_ST[4] = {0, 9216, 11520, 12096};

typedef __attribute__((ext_vector_type(8))) short short8;            // bf16x8 MFMA frag
typedef __attribute__((ext_vector_type(4))) float f32x4;
typedef __attribute__((ext_vector_type(2))) float f32x2;

__device__ __forceinline__ unsigned short f2bf(float f) {
    unsigned int u = __float_as_uint(f);
    unsigned int r = (u + 0x7FFFu + ((u >> 16) & 1u)) >> 16;   // RNE
    return (unsigned short)r;
}
__device__ __forceinline__ float bf2f(unsigned short b) {
    return __uint_as_float(((unsigned int)b) << 16);
}

// packed fp32 FMA: acc(2ch) += bf16pair(u) * w(pair). 2 unpack + 1 v_pk_fma_f32.
__device__ __forceinline__ void pkfma(f32x2& a, unsigned int u, f32x2 w) {
    f32x2 v;
    v.x = __uint_as_float(u << 16);
    v.y = __uint_as_float(u & 0xffff0000u);
    asm("v_pk_fma_f32 %0, %1, %2, %0" : "+v"(a) : "v"(v), "v"(w));
}

// ---------------- weight prep: transpose + f32->bf16 ----------------
__global__ __launch_bounds__(256) void prep_weights(
    const float* __restrict__ W_off, const float* __restrict__ W_attn,
    const float* __restrict__ W_val, const float* __restrict__ W_out,
    unsigned short* __restrict__ WT_oa, unsigned short* __restrict__ WT_val,
    unsigned short* __restrict__ WT_out)
{
    const int gid = blockIdx.x * 256 + threadIdx.x;   // 896*256 total
    const int k = gid & 255;
    const int n = gid >> 8;
    if (n < 384) {
        const float v = (n < 256) ? W_off[k * 256 + n] : W_attn[k * 128 + (n - 256)];
        WT_oa[n * 256 + k] = f2bf(v);
    } else if (n < 640) {
        const int nn = n - 384;
        WT_val[nn * 256 + k] = f2bf(W_val[k * 256 + nn]);
    } else {
        const int nn = n - 640;
        WT_out[nn * 256 + k] = f2bf(W_out[k * 256 + nn]);
    }
}

// ---------------- bf16 MFMA GEMM with register-double-buffered staging ----------------
template <int NTW, bool A_BF16, bool OUT_BF16>
__global__ __launch_bounds__(256) void gemm_mfma(
    const void* __restrict__ Av, const unsigned short* __restrict__ Wt,
    const float* __restrict__ bias0, const float* __restrict__ bias1, int nsplit,
    void* __restrict__ Cv, int N)
{
    constexpr int NB = NTW * 64;
    constexpr int K  = 256;
    __shared__ __align__(16) unsigned short As[64][40];
    __shared__ __align__(16) unsigned short Bs[NB][40];

    const int tid = threadIdx.x;
    const int m0 = blockIdx.y * 64;
    const int n0 = blockIdx.x * NB;
    const int w  = tid >> 6;
    const int l  = tid & 63;
    const int lm = l & 15;
    const int lq = l >> 4;

    const int sr = tid >> 2;          // staging row 0..63
    const int kg = (tid & 3) * 8;     // staging k offset 0,8,16,24

    float4 pa0, pa1; short8 pa_bf;    // A prefetch regs
    short8 pb[NTW];                   // B prefetch regs

    auto gload = [&](int k0) {
        if (A_BF16) {
            const unsigned short* A = (const unsigned short*)Av;
            pa_bf = *(const short8*)&A[(size_t)(m0 + sr) * K + k0 + kg];
        } else {
            const float* A = (const float*)Av;
            const float* ap = &A[(size_t)(m0 + sr) * K + k0 + kg];
            pa0 = *(const float4*)ap;
            pa1 = *(const float4*)(ap + 4);
        }
        #pragma unroll
        for (int i = 0; i < NTW; ++i) {
            const int slot = tid + i * 256;
            const int n  = slot >> 2;
            const int kk = (slot & 3) * 8;
            pb[i] = *(const short8*)&Wt[(size_t)(n0 + n) * K + k0 + kk];
        }
    };

    f32x4 acc[4][NTW];
    #pragma unroll
    for (int rg = 0; rg < 4; ++rg)
        #pragma unroll
        for (int nt = 0; nt < NTW; ++nt)
            acc[rg][nt] = (f32x4){0.f, 0.f, 0.f, 0.f};

    gload(0);
    #pragma unroll 2
    for (int k0 = 0; k0 < K; k0 += 32) {
        // ---- store prefetched tile to LDS ----
        if (A_BF16) {
            *(short8*)&As[sr][kg] = pa_bf;
        } else {
            uint4 pk;
            pk.x = (unsigned int)f2bf(pa0.x) | ((unsigned int)f2bf(pa0.y) << 16);
            pk.y = (unsigned int)f2bf(pa0.z) | ((unsigned int)f2bf(pa0.w) << 16);
            pk.z = (unsigned int)f2bf(pa1.x) | ((unsigned int)f2bf(pa1.y) << 16);
            pk.w = (unsigned int)f2bf(pa1.z) | ((unsigned int)f2bf(pa1.w) << 16);
            *(uint4*)&As[sr][kg] = pk;
        }
        #pragma unroll
        for (int i = 0; i < NTW; ++i) {
            const int slot = tid + i * 256;
            const int n  = slot >> 2;
            const int kk = (slot & 3) * 8;
            *(short8*)&Bs[n][kk] = pb[i];
        }
        __syncthreads();

        if (k0 + 32 < K) gload(k0 + 32);   // issue next tile's loads now

        short8 af[4];
        #pragma unroll
        for (int rg = 0; rg < 4; ++rg)
            af[rg] = *(const short8*)&As[rg * 16 + lm][lq * 8];
        #pragma unroll
        for (int nt = 0; nt < NTW; ++nt) {
            const short8 bf = *(const short8*)&Bs[(w * NTW + nt) * 16 + lm][lq * 8];
            #pragma unroll
            for (int rg = 0; rg < 4; ++rg)
                acc[rg][nt] = __builtin_amdgcn_mfma_f32_16x16x32_bf16(af[rg], bf, acc[rg][nt], 0, 0, 0);
        }
        __syncthreads();
    }

    // ---- epilogue ----
    #pragma unroll
    for (int nt = 0; nt < NTW; ++nt) {
        const int col = n0 + (w * NTW + nt) * 16 + lm;
        const float b = (col < nsplit) ? bias0[col] : bias1[col - nsplit];
        #pragma unroll
        for (int rg = 0; rg < 4; ++rg)
            #pragma unroll
            for (int r = 0; r < 4; ++r) {
                const int row = m0 + rg * 16 + lq * 4 + r;
                const float v = acc[rg][nt][r] + b;
                if (OUT_BF16) ((unsigned short*)Cv)[(size_t)row * N + col] = f2bf(v);
                else          ((float*)Cv)[(size_t)row * N + col] = v;
            }
    }
}

// ---------------- loc + softmax (in place over OA [row][384]) ----------------
__global__ __launch_bounds__(256) void loc_aw_kernel(
    float* __restrict__ OA, const float* __restrict__ refp)
{
    const int tid = threadIdx.x;
    const int row = blockIdx.x * 2 + (tid >> 7);
    const int t = tid & 127;
    const int l = (t >> 2) & 3;
    float* rowp = OA + (size_t)row * 384;

    float logit = rowp[256 + t];
    float m = logit;
    #pragma unroll
    for (int d = 8; d >= 1; d >>= 1) m = fmaxf(m, __shfl_xor(m, d, 16));
    float e = __expf(logit - m);
    float s = e;
    #pragma unroll
    for (int d = 8; d >= 1; d >>= 1) s += __shfl_xor(s, d, 16);
    rowp[256 + t] = e / s;

    const float ox = rowp[t * 2 + 0];
    const float oy = rowp[t * 2 + 1];
    const float rx = refp[(size_t)row * 8 + l * 2 + 0];
    const float ry = refp[(size_t)row * 8 + l * 2 + 1];
    const float Wl = (float)LVL_W[l];
    const float Hl = (float)LVL_H[l];
    const float lx = rx + ox / Wl;      // mimic reference op order
    const float ly = ry + oy / Hl;
    rowp[t * 2 + 0] = lx * Wl - 0.5f;
    rowp[t * 2 + 1] = ly * Hl - 0.5f;
}

// ---------------- bilinear sampling v2 ----------------
// Block = 256 threads = 4 waves, 4 rows (one row per wave).
// Phase 1 (cooperative prep): 512 samples (4 rows x 8 heads x 16 lp); each of the
//   256 threads computes 2 samples' 4 corner weights (premult by aw, f32, stored
//   DUPLICATED as pairs for v_pk_fma) + 4 corner byte offsets -> LDS, stride 12 u32
//   (48B) which lands the 8 heads on disjoint bank groups (12h mod 32).
// Phase 2 (main): wave w = row; lane: half=l>>5 handles 8 lps (2 levels),
//   head=(l>>2)&7, 8 channels/lane via uint4 (16B) loads. Corner consume =
//   4x v_pk_fma_f32 (2ch each) + 8 unpack ops. Double-buffered lp pipeline.
// Phase 3: cross-half reduce via shfl_xor(32) (same sum order as LDS version).
__global__ __launch_bounds__(256) void sample_kernel(
    const unsigned short* __restrict__ V,   // bf16 [b, pix, 256]
    const float* __restrict__ OA,           // [row][384]: coords then weights
    unsigned short* __restrict__ ACC)       // bf16 [row][256]
{
    __shared__ unsigned int pr[512 * 12];   // 24 KB: per sample {off0..3, w0,w0,w1,w1,w2,w2,w3,w3}

    const int tid = threadIdx.x;

    // ---- phase 1: cooperative prep (2 samples per thread) ----
    #pragma unroll
    for (int ss = 0; ss < 2; ++ss) {
        const int s  = tid + ss * 256;      // s = lp*32 + r*8 + h
        const int lp = s >> 5;
        const int r  = (s >> 3) & 3;
        const int h  = s & 7;
        const int lvl = lp >> 2;
        const int Wl = LVL_W[lvl], Hl = LVL_H[lvl], st = LVL_ST[lvl];
        const float* rowp = OA + (size_t)(blockIdx.x * 4 + r) * 384;

        const float gx  = rowp[h * 32 + lp * 2 + 0];
        const float gy  = rowp[h * 32 + lp * 2 + 1];
        const float wgt = rowp[256 + h * 16 + lp];

        const float fx = floorf(gx), fy = floorf(gy);
        const float wx = gx - fx,    wy = gy - fy;
        const int x0 = (int)fx, y0 = (int)fy;
        const int x1 = x0 + 1,  y1 = y0 + 1;

        const bool bx0 = ((unsigned)x0 < (unsigned)Wl);
        const bool bx1 = ((unsigned)x1 < (unsigned)Wl);
        const bool by0 = ((unsigned)y0 < (unsigned)Hl);
        const bool by1 = ((unsigned)y1 < (unsigned)Hl);
        const float w00 = (bx0 && by0) ? (1.f - wx) * (1.f - wy) * wgt : 0.f;
        const float w10 = (bx1 && by0) ? wx * (1.f - wy) * wgt : 0.f;
        const float w01 = (bx0 && by1) ? (1.f - wx) * wy * wgt : 0.f;
        const float w11 = (bx1 && by1) ? wx * wy * wgt : 0.f;

        const int cx0 = min(max(x0, 0), Wl - 1);
        const int cx1 = min(max(x1, 0), Wl - 1);
        const int cy0 = min(max(y0, 0), Hl - 1);
        const int cy1 = min(max(y1, 0), Hl - 1);

        unsigned int* p = &pr[s * 12];
        uint4 o;
        o.x = (unsigned int)(st + cy0 * Wl + cx0) * 512u;   // byte offsets (pix*256ch*2B)
        o.y = (unsigned int)(st + cy0 * Wl + cx1) * 512u;
        o.z = (unsigned int)(st + cy1 * Wl + cx0) * 512u;
        o.w = (unsigned int)(st + cy1 * Wl + cx1) * 512u;
        *(uint4*)p = o;
        uint4 wA, wB;
        wA.x = __float_as_uint(w00); wA.y = wA.x;
        wA.z = __float_as_uint(w10); wA.w = wA.z;
        wB.x = __float_as_uint(w01); wB.y = wB.x;
        wB.z = __float_as_uint(w11); wB.w = wB.z;
        *(uint4*)(p + 4) = wA;
        *(uint4*)(p + 8) = wB;
    }
    __syncthreads();

    // ---- phase 2: sampling main loop ----
    const int w    = tid >> 6;             // wave = row within block
    const int l    = tid & 63;
    const int half = l >> 5;               // lp group (levels 0,1 vs 2,3)
    const int head = (l >> 2) & 7;
    const int c16  = (l & 3) * 16;         // byte offset of this lane's 8-channel group

    const int row  = __builtin_amdgcn_readfirstlane(blockIdx.x * 4 + w);
    const int b    = row / LQ;
    const char* vrow = (const char*)V + (size_t)b * ((size_t)LQ * 512);
    const unsigned int lane_byte = (unsigned int)(head * 64 + c16);
    const int sid0 = half * 8 * 32 + w * 8 + head;   // + j*32 per lp step

    unsigned int ofs[2][4];
    f32x2 wp[2][4];
    uint4 dat[2][4];
    f32x2 acc[4];
    #pragma unroll
    for (int i = 0; i < 4; ++i) acc[i] = (f32x2){0.f, 0.f};

    auto ldprep = [&](int j, int buf) {
        const unsigned int* p = &pr[(sid0 + j * 32) * 12];
        const uint4 o = *(const uint4*)p;                  // ds_read_b128
        ofs[buf][0] = o.x; ofs[buf][1] = o.y; ofs[buf][2] = o.z; ofs[buf][3] = o.w;
        #pragma unroll
        for (int c = 0; c < 4; ++c)
            wp[buf][c] = *(const f32x2*)(p + 4 + 2 * c);   // ds_read_b64, pair-ready
    };
    auto ldval = [&](int buf) {
        #pragma unroll
        for (int c = 0; c < 4; ++c)
            dat[buf][c] = *(const uint4*)(vrow + (lane_byte + ofs[buf][c]));
    };
    auto consume = [&](int buf) {
        #pragma unroll
        for (int c = 0; c < 4; ++c) {
            const uint4 d = dat[buf][c];
            const f32x2 ww = wp[buf][c];
            pkfma(acc[0], d.x, ww);
            pkfma(acc[1], d.y, ww);
            pkfma(acc[2], d.z, ww);
            pkfma(acc[3], d.w, ww);
        }
    };

    ldprep(0, 0);
    ldval(0);
    #pragma unroll
    for (int j = 0; j < 8; ++j) {
        if (j < 7) {
            ldprep(j + 1, (j + 1) & 1);
            ldval((j + 1) & 1);
        }
        consume(j & 1);
    }

    // ---- phase 3: cross-half reduce + write ----
    #pragma unroll
    for (int i = 0; i < 4; ++i) {
        acc[i].x += __shfl_xor(acc[i].x, 32);
        acc[i].y += __shfl_xor(acc[i].y, 32);
    }
    if (half == 0) {
        uint4 o;
        o.x = (unsigned int)f2bf(acc[0].x) | ((unsigned int)f2bf(acc[0].y) << 16);
        o.y = (unsigned int)f2bf(acc[1].x) | ((unsigned int)f2bf(acc[1].y) << 16);
        o.z = (unsigned int)f2bf(acc[2].x) | ((unsigned int)f2bf(acc[2].y) << 16);
        o.w = (unsigned int)f2bf(acc[3].x) | ((unsigned int)f2bf(acc[3].y) << 16);
        *(uint4*)((char*)(ACC + (size_t)row * EMBED) + head * 64 + c16) = o;
    }
}

// ---------------- launch ----------------
extern "C" void kernel_launch(void* const* d_in, const int* in_sizes, int n_in,
                              void* d_out, int out_size, void* d_ws, size_t ws_size,
                              hipStream_t stream) {
    const float* query  = (const float*)d_in[0];
    const float* refp   = (const float*)d_in[1];
    const float* value  = (const float*)d_in[2];
    // d_in[3] = value_spatial_shapes (static, hard-coded)
    const float* W_off  = (const float*)d_in[4];
    const float* b_off  = (const float*)d_in[5];
    const float* W_attn = (const float*)d_in[6];
    const float* b_attn = (const float*)d_in[7];
    const float* W_val  = (const float*)d_in[8];
    const float* b_val  = (const float*)d_in[9];
    const float* W_out  = (const float*)d_in[10];
    const float* b_out  = (const float*)d_in[11];
    float* out = (float*)d_out;

    // ---- workspace layout ----
    unsigned short* WT_oa  = (unsigned short*)d_ws;          // [384][256] bf16
    unsigned short* WT_val = WT_oa  + 384 * 256;             // [256][256] bf16
    unsigned short* WT_out = WT_val + 256 * 256;             // [256][256] bf16
    unsigned short* V      = WT_out + 256 * 256;             // [NROW][256] bf16
    float*          OA     = (float*)(V + (size_t)NROW * EMBED);        // [NROW][384] f32
    unsigned short* ACCb   = (unsigned short*)(OA + (size_t)NROW * 384); // [NROW][256] bf16

    dim3 blk(256);

    // 0. weight transpose + convert
    prep_weights<<<896, blk, 0, stream>>>(W_off, W_attn, W_val, W_out,
                                          WT_oa, WT_val, WT_out);
    // 1. V = bf16(value @ W_val + b_val)
    gemm_mfma<4, false, true><<<dim3(1, NROW / 64), blk, 0, stream>>>(
        value, WT_val, b_val, b_val, 256, V, 256);
    // 2. OA = query @ [W_off | W_attn] + bias  (N=384, two 192-col blocks)
    gemm_mfma<3, false, false><<<dim3(2, NROW / 64), blk, 0, stream>>>(
        query, WT_oa, b_off, b_attn, 256, OA, 384);
    // 3. softmax + pixel coords (in place over OA)
    loc_aw_kernel<<<NROW / 2, blk, 0, stream>>>(OA, refp);
    // 4. deformable sampling -> bf16 ACC
    sample_kernel<<<NROW / 4, blk, 0, stream>>>(V, OA, ACCb);
    // 5. out = ACC @ W_out + b_out
    gemm_mfma<4, true, false><<<dim3(1, NROW / 64), blk, 0, stream>>>(
        ACCb, WT_out, b_out, b_out, 256, out, 256);
}

// Round 2
// 368.303 us; speedup vs baseline: 1.0396x; 1.0396x over previous
//
#include <hip/hip_runtime.h>
#include <hip/hip_bf16.h>

// ---------------- static problem constants ----------------
static constexpr int BS     = 4;
static constexpr int EMBED  = 256;
static constexpr int HEADS  = 8;
static constexpr int LEVELS = 4;
static constexpr int POINTS = 4;
static constexpr int HD     = 32;               // EMBED / HEADS
static constexpr int LQ     = 12240;            // sum of level areas
static constexpr int NROW   = BS * LQ;          // 48960 rows
static constexpr int LVL_W[4]  = {96, 48, 24, 12};
static constexpr int LVL_H[4]  = {96, 48, 24, 12};
static constexpr int LVL_ST[4] = {0, 9216, 11520, 12096};

typedef __attribute__((ext_vector_type(8))) short short8;            // bf16x8 MFMA frag
typedef __attribute__((ext_vector_type(4))) float f32x4;
typedef __attribute__((ext_vector_type(2))) float f32x2;

__device__ __forceinline__ unsigned short f2bf(float f) {
    unsigned int u = __float_as_uint(f);
    unsigned int r = (u + 0x7FFFu + ((u >> 16) & 1u)) >> 16;   // RNE
    return (unsigned short)r;
}

// packed fp32 FMA: acc += v * w (2 lanes of f32 each)
__device__ __forceinline__ void pkfma(f32x2& a, f32x2 v, f32x2 w) {
    asm("v_pk_fma_f32 %0, %1, %2, %0" : "+v"(a) : "v"(v), "v"(w));
}

// ---------------- weight prep: transpose + f32->bf16 ----------------
__global__ __launch_bounds__(256) void prep_weights(
    const float* __restrict__ W_off, const float* __restrict__ W_attn,
    const float* __restrict__ W_val, const float* __restrict__ W_out,
    unsigned short* __restrict__ WT_oa, unsigned short* __restrict__ WT_val,
    unsigned short* __restrict__ WT_out)
{
    const int gid = blockIdx.x * 256 + threadIdx.x;   // 896*256 total
    const int k = gid & 255;
    const int n = gid >> 8;
    if (n < 384) {
        const float v = (n < 256) ? W_off[k * 256 + n] : W_attn[k * 128 + (n - 256)];
        WT_oa[n * 256 + k] = f2bf(v);
    } else if (n < 640) {
        const int nn = n - 384;
        WT_val[nn * 256 + k] = f2bf(W_val[k * 256 + nn]);
    } else {
        const int nn = n - 640;
        WT_out[nn * 256 + k] = f2bf(W_out[k * 256 + nn]);
    }
}

// ---------------- bf16 MFMA GEMM with register-double-buffered staging ----------------
template <int NTW, bool A_BF16, bool OUT_BF16>
__global__ __launch_bounds__(256) void gemm_mfma(
    const void* __restrict__ Av, const unsigned short* __restrict__ Wt,
    const float* __restrict__ bias0, const float* __restrict__ bias1, int nsplit,
    void* __restrict__ Cv, int N)
{
    constexpr int NB = NTW * 64;
    constexpr int K  = 256;
    __shared__ __align__(16) unsigned short As[64][40];
    __shared__ __align__(16) unsigned short Bs[NB][40];

    const int tid = threadIdx.x;
    const int m0 = blockIdx.y * 64;
    const int n0 = blockIdx.x * NB;
    const int w  = tid >> 6;
    const int l  = tid & 63;
    const int lm = l & 15;
    const int lq = l >> 4;

    const int sr = tid >> 2;          // staging row 0..63
    const int kg = (tid & 3) * 8;     // staging k offset 0,8,16,24

    float4 pa0, pa1; short8 pa_bf;    // A prefetch regs
    short8 pb[NTW];                   // B prefetch regs

    auto gload = [&](int k0) {
        if (A_BF16) {
            const unsigned short* A = (const unsigned short*)Av;
            pa_bf = *(const short8*)&A[(size_t)(m0 + sr) * K + k0 + kg];
        } else {
            const float* A = (const float*)Av;
            const float* ap = &A[(size_t)(m0 + sr) * K + k0 + kg];
            pa0 = *(const float4*)ap;
            pa1 = *(const float4*)(ap + 4);
        }
        #pragma unroll
        for (int i = 0; i < NTW; ++i) {
            const int slot = tid + i * 256;
            const int n  = slot >> 2;
            const int kk = (slot & 3) * 8;
            pb[i] = *(const short8*)&Wt[(size_t)(n0 + n) * K + k0 + kk];
        }
    };

    f32x4 acc[4][NTW];
    #pragma unroll
    for (int rg = 0; rg < 4; ++rg)
        #pragma unroll
        for (int nt = 0; nt < NTW; ++nt)
            acc[rg][nt] = (f32x4){0.f, 0.f, 0.f, 0.f};

    gload(0);
    #pragma unroll 2
    for (int k0 = 0; k0 < K; k0 += 32) {
        // ---- store prefetched tile to LDS ----
        if (A_BF16) {
            *(short8*)&As[sr][kg] = pa_bf;
        } else {
            uint4 pk;
            pk.x = (unsigned int)f2bf(pa0.x) | ((unsigned int)f2bf(pa0.y) << 16);
            pk.y = (unsigned int)f2bf(pa0.z) | ((unsigned int)f2bf(pa0.w) << 16);
            pk.z = (unsigned int)f2bf(pa1.x) | ((unsigned int)f2bf(pa1.y) << 16);
            pk.w = (unsigned int)f2bf(pa1.z) | ((unsigned int)f2bf(pa1.w) << 16);
            *(uint4*)&As[sr][kg] = pk;
        }
        #pragma unroll
        for (int i = 0; i < NTW; ++i) {
            const int slot = tid + i * 256;
            const int n  = slot >> 2;
            const int kk = (slot & 3) * 8;
            *(short8*)&Bs[n][kk] = pb[i];
        }
        __syncthreads();

        if (k0 + 32 < K) gload(k0 + 32);   // issue next tile's loads now

        short8 af[4];
        #pragma unroll
        for (int rg = 0; rg < 4; ++rg)
            af[rg] = *(const short8*)&As[rg * 16 + lm][lq * 8];
        #pragma unroll
        for (int nt = 0; nt < NTW; ++nt) {
            const short8 bf = *(const short8*)&Bs[(w * NTW + nt) * 16 + lm][lq * 8];
            #pragma unroll
            for (int rg = 0; rg < 4; ++rg)
                acc[rg][nt] = __builtin_amdgcn_mfma_f32_16x16x32_bf16(af[rg], bf, acc[rg][nt], 0, 0, 0);
        }
        __syncthreads();
    }

    // ---- epilogue ----
    #pragma unroll
    for (int nt = 0; nt < NTW; ++nt) {
        const int col = n0 + (w * NTW + nt) * 16 + lm;
        const float b = (col < nsplit) ? bias0[col] : bias1[col - nsplit];
        #pragma unroll
        for (int rg = 0; rg < 4; ++rg)
            #pragma unroll
            for (int r = 0; r < 4; ++r) {
                const int row = m0 + rg * 16 + lq * 4 + r;
                const float v = acc[rg][nt][r] + b;
                if (OUT_BF16) ((unsigned short*)Cv)[(size_t)row * N + col] = f2bf(v);
                else          ((float*)Cv)[(size_t)row * N + col] = v;
            }
    }
}

// ---------------- bilinear sampling v3 (loc+softmax fused in) ----------------
// Block = 256 threads = 4 waves, 4 rows (one row per wave).
//
// Phase 1 (cooperative prep, fused softmax+coords): thread t handles group
//   g = t&31 (r = g>>3, h = g&7) and lp pair {L, L+8} with L = t>>5.
//   Softmax over the 16 logits of (r,h): LDS tree-reduce across the 8 threads
//   (stride 32, cross-wave) via scratch unioned into pr_w space. Coords read
//   raw OA offsets + refp, transform to pixel space, compute 4 corner byte
//   offsets + 4 aw-premultiplied corner weights per sample.
//   Storage: pr_o[s][4] = corner byte offsets; pr_w[s][4] = weights
//   {w00,w10,w01,w11} (s = lp*32 + g). Head stride = 4 dwords -> 8 heads hit
//   all 32 banks exactly once -> conflict-free b128 reads.
//
// Phase 2: wave w = row; lane: half=l>>5 (lp 0-7 vs 8-15), head=(l>>2)&7,
//   8 channels/lane via uint4 loads. Consume packs CORNER pairs:
//   pa=(d_c0.ch, d_c1.ch) * (w_c0,w_c1) via v_pk_fma_f32; accumulator keeps
//   even/odd-corner partials per channel, folded at epilogue. Double-buffered.
// Phase 3: fold pairs, cross-half shfl reduce, bf16 write.
__global__ __launch_bounds__(256, 8) void sample_kernel(
    const unsigned short* __restrict__ V,   // bf16 [b, pix, 256]
    const float* __restrict__ OA,           // [row][384]: raw offsets + logits
    const float* __restrict__ refp,         // [row][4][2]
    unsigned short* __restrict__ ACC)       // bf16 [row][256]
{
    __shared__ __align__(16) unsigned int pr_o[512][4];   // 8 KB corner byte offsets
    __shared__ __align__(16) unsigned int pr_w[512][4];   // 8 KB corner weights (f32 bits)

    const int tid = threadIdx.x;

    // ---- phase 1: softmax + coords + corner prep ----
    {
        const int g = tid & 31;            // r*8 + h
        const int r = g >> 3;
        const int h = g & 7;
        const int L = tid >> 5;            // 0..7
        const int prow = blockIdx.x * 4 + r;
        const float* rowp = OA + (size_t)prow * 384;

        const float lg0 = rowp[256 + h * 16 + L];
        const float lg1 = rowp[256 + h * 16 + L + 8];

        float* smax = (float*)pr_w;        // [8][33] scratch (unioned, rewritten later)
        float* ssum = smax + 264;
        smax[L * 33 + g] = fmaxf(lg0, lg1);
        __syncthreads();
        float m = smax[g];
        #pragma unroll
        for (int k = 1; k < 8; ++k) m = fmaxf(m, smax[k * 33 + g]);
        const float e0 = __expf(lg0 - m);
        const float e1 = __expf(lg1 - m);
        ssum[L * 33 + g] = e0 + e1;
        __syncthreads();
        float sden = ssum[g];
        #pragma unroll
        for (int k = 1; k < 8; ++k) sden += ssum[k * 33 + g];
        const float inv = 1.0f / sden;

        uint4 wstash[2];
        int   sidx[2];
        #pragma unroll
        for (int ss = 0; ss < 2; ++ss) {
            const int lp  = L + ss * 8;
            const int s   = lp * 32 + g;
            const int lvl = lp >> 2;
            const int Wl = LVL_W[lvl], Hl = LVL_H[lvl], st = LVL_ST[lvl];

            const float2 oxy = *(const float2*)&rowp[h * 32 + lp * 2];
            const float2 rxy = *(const float2*)&refp[(size_t)prow * 8 + lvl * 2];
            const float wgt = (ss ? e1 : e0) * inv;

            // mimic reference op order: lx = rx + ox/Wl; gx = lx*Wl - 0.5
            const float gx = (rxy.x + oxy.x / (float)Wl) * (float)Wl - 0.5f;
            const float gy = (rxy.y + oxy.y / (float)Hl) * (float)Hl - 0.5f;

            const float fx = floorf(gx), fy = floorf(gy);
            const float wx = gx - fx,    wy = gy - fy;
            const int x0 = (int)fx, y0 = (int)fy;
            const int x1 = x0 + 1,  y1 = y0 + 1;

            const bool bx0 = ((unsigned)x0 < (unsigned)Wl);
            const bool bx1 = ((unsigned)x1 < (unsigned)Wl);
            const bool by0 = ((unsigned)y0 < (unsigned)Hl);
            const bool by1 = ((unsigned)y1 < (unsigned)Hl);
            const float w00 = (bx0 && by0) ? (1.f - wx) * (1.f - wy) * wgt : 0.f;
            const float w10 = (bx1 && by0) ? wx * (1.f - wy) * wgt : 0.f;
            const float w01 = (bx0 && by1) ? (1.f - wx) * wy * wgt : 0.f;
            const float w11 = (bx1 && by1) ? wx * wy * wgt : 0.f;

            const int cx0 = min(max(x0, 0), Wl - 1);
            const int cx1 = min(max(x1, 0), Wl - 1);
            const int cy0 = min(max(y0, 0), Hl - 1);
            const int cy1 = min(max(y1, 0), Hl - 1);

            uint4 o;
            o.x = (unsigned int)(st + cy0 * Wl + cx0) * 512u;   // pix * 256ch * 2B
            o.y = (unsigned int)(st + cy0 * Wl + cx1) * 512u;
            o.z = (unsigned int)(st + cy1 * Wl + cx0) * 512u;
            o.w = (unsigned int)(st + cy1 * Wl + cx1) * 512u;
            *(uint4*)&pr_o[s][0] = o;

            uint4 wv;
            wv.x = __float_as_uint(w00); wv.y = __float_as_uint(w10);
            wv.z = __float_as_uint(w01); wv.w = __float_as_uint(w11);
            wstash[ss] = wv;
            sidx[ss] = s;
        }
        __syncthreads();                   // all scratch reads done
        *(uint4*)&pr_w[sidx[0]][0] = wstash[0];
        *(uint4*)&pr_w[sidx[1]][0] = wstash[1];
    }
    __syncthreads();

    // ---- phase 2: sampling main loop ----
    const int w    = tid >> 6;             // wave = row within block
    const int l    = tid & 63;
    const int half = l >> 5;               // lp group (0-7 vs 8-15)
    const int head = (l >> 2) & 7;
    const int c16  = (l & 3) * 16;         // byte offset of 8-channel group

    const int row  = __builtin_amdgcn_readfirstlane(blockIdx.x * 4 + w);
    const int b    = row / LQ;
    const char* vrow = (const char*)V + (size_t)b * ((size_t)LQ * 512);
    const unsigned int lane_byte = (unsigned int)(head * 64 + c16);
    const int sid0 = half * 256 + w * 8 + head;   // + j*32 per lp step

    uint4 dat[2][4];
    f32x2 accA[4], accB[4];                // even/odd-corner partials, ch pairs
    #pragma unroll
    for (int i = 0; i < 4; ++i) { accA[i] = (f32x2){0.f,0.f}; accB[i] = (f32x2){0.f,0.f}; }

    auto ldissue = [&](int j, int buf) {
        const uint4 o = *(const uint4*)&pr_o[sid0 + j * 32][0];   // ds_read_b128
        dat[buf][0] = *(const uint4*)(vrow + (lane_byte + o.x));
        dat[buf][1] = *(const uint4*)(vrow + (lane_byte + o.y));
        dat[buf][2] = *(const uint4*)(vrow + (lane_byte + o.z));
        dat[buf][3] = *(const uint4*)(vrow + (lane_byte + o.w));
    };
    auto pkstep = [&](f32x2& A, f32x2& B, unsigned u0, unsigned u1, f32x2 w2) {
        f32x2 pa, pb;
        pa.x = __uint_as_float(u0 << 16);
        pa.y = __uint_as_float(u1 << 16);
        pb.x = __uint_as_float(u0 & 0xffff0000u);
        pb.y = __uint_as_float(u1 & 0xffff0000u);
        pkfma(A, pa, w2);
        pkfma(B, pb, w2);
    };
    auto consume = [&](int j, int buf) {
        const f32x4 wv = *(const f32x4*)&pr_w[sid0 + j * 32][0];  // ds_read_b128
        f32x2 w01; w01.x = wv.x; w01.y = wv.y;
        f32x2 w23; w23.x = wv.z; w23.y = wv.w;
        const uint4 d0 = dat[buf][0], d1 = dat[buf][1];
        pkstep(accA[0], accB[0], d0.x, d1.x, w01);
        pkstep(accA[1], accB[1], d0.y, d1.y, w01);
        pkstep(accA[2], accB[2], d0.z, d1.z, w01);
        pkstep(accA[3], accB[3], d0.w, d1.w, w01);
        const uint4 d2 = dat[buf][2], d3 = dat[buf][3];
        pkstep(accA[0], accB[0], d2.x, d3.x, w23);
        pkstep(accA[1], accB[1], d2.y, d3.y, w23);
        pkstep(accA[2], accB[2], d2.z, d3.z, w23);
        pkstep(accA[3], accB[3], d2.w, d3.w, w23);
    };

    ldissue(0, 0);
    #pragma unroll
    for (int j = 0; j < 8; ++j) {
        if (j < 7) ldissue(j + 1, (j + 1) & 1);
        consume(j, j & 1);
    }

    // ---- phase 3: fold corner partials, cross-half reduce, write ----
    float c[8];
    #pragma unroll
    for (int i = 0; i < 4; ++i) {
        c[2 * i]     = accA[i].x + accA[i].y;
        c[2 * i + 1] = accB[i].x + accB[i].y;
    }
    #pragma unroll
    for (int i = 0; i < 8; ++i) c[i] += __shfl_xor(c[i], 32);

    if (half == 0) {
        uint4 o;
        o.x = (unsigned int)f2bf(c[0]) | ((unsigned int)f2bf(c[1]) << 16);
        o.y = (unsigned int)f2bf(c[2]) | ((unsigned int)f2bf(c[3]) << 16);
        o.z = (unsigned int)f2bf(c[4]) | ((unsigned int)f2bf(c[5]) << 16);
        o.w = (unsigned int)f2bf(c[6]) | ((unsigned int)f2bf(c[7]) << 16);
        *(uint4*)((char*)(ACC + (size_t)row * EMBED) + head * 64 + c16) = o;
    }
}

// ---------------- launch ----------------
extern "C" void kernel_launch(void* const* d_in, const int* in_sizes, int n_in,
                              void* d_out, int out_size, void* d_ws, size_t ws_size,
                              hipStream_t stream) {
    const float* query  = (const float*)d_in[0];
    const float* refp   = (const float*)d_in[1];
    const float* value  = (const float*)d_in[2];
    // d_in[3] = value_spatial_shapes (static, hard-coded)
    const float* W_off  = (const float*)d_in[4];
    const float* b_off  = (const float*)d_in[5];
    const float* W_attn = (const float*)d_in[6];
    const float* b_attn = (const float*)d_in[7];
    const float* W_val  = (const float*)d_in[8];
    const float* b_val  = (const float*)d_in[9];
    const float* W_out  = (const float*)d_in[10];
    const float* b_out  = (const float*)d_in[11];
    float* out = (float*)d_out;

    // ---- workspace layout ----
    unsigned short* WT_oa  = (unsigned short*)d_ws;          // [384][256] bf16
    unsigned short* WT_val = WT_oa  + 384 * 256;             // [256][256] bf16
    unsigned short* WT_out = WT_val + 256 * 256;             // [256][256] bf16
    unsigned short* V      = WT_out + 256 * 256;             // [NROW][256] bf16
    float*          OA     = (float*)(V + (size_t)NROW * EMBED);        // [NROW][384] f32
    unsigned short* ACCb   = (unsigned short*)(OA + (size_t)NROW * 384); // [NROW][256] bf16

    dim3 blk(256);

    // 0. weight transpose + convert
    prep_weights<<<896, blk, 0, stream>>>(W_off, W_attn, W_val, W_out,
                                          WT_oa, WT_val, WT_out);
    // 1. V = bf16(value @ W_val + b_val)
    gemm_mfma<4, false, true><<<dim3(1, NROW / 64), blk, 0, stream>>>(
        value, WT_val, b_val, b_val, 256, V, 256);
    // 2. OA = query @ [W_off | W_attn] + bias  (N=384, raw offsets + logits)
    gemm_mfma<3, false, false><<<dim3(2, NROW / 64), blk, 0, stream>>>(
        query, WT_oa, b_off, b_attn, 256, OA, 384);
    // 3. deformable sampling (softmax+coords fused) -> bf16 ACC
    sample_kernel<<<NROW / 4, blk, 0, stream>>>(V, OA, refp, ACCb);
    // 4. out = ACC @ W_out + b_out
    gemm_mfma<4, true, false><<<dim3(1, NROW / 64), blk, 0, stream>>>(
        ACCb, WT_out, b_out, b_out, 256, out, 256);
}

// Round 3
// 332.334 us; speedup vs baseline: 1.1521x; 1.1082x over previous
//
#include <hip/hip_runtime.h>
#include <hip/hip_bf16.h>

// ---------------- static problem constants ----------------
static constexpr int BS     = 4;
static constexpr int EMBED  = 256;
static constexpr int HEADS  = 8;
static constexpr int LEVELS = 4;
static constexpr int POINTS = 4;
static constexpr int HD     = 32;               // EMBED / HEADS
static constexpr int LQ     = 12240;            // sum of level areas
static constexpr int NROW   = BS * LQ;          // 48960 rows
static constexpr int LVL_W[4]  = {96, 48, 24, 12};
static constexpr int LVL_H[4]  = {96, 48, 24, 12};
static constexpr int LVL_ST[4] = {0, 9216, 11520, 12096};

typedef __attribute__((ext_vector_type(8))) short short8;            // bf16x8 MFMA frag
typedef __attribute__((ext_vector_type(4))) float f32x4;
typedef __attribute__((ext_vector_type(2))) float f32x2;

__device__ __forceinline__ unsigned short f2bf(float f) {
    unsigned int u = __float_as_uint(f);
    unsigned int r = (u + 0x7FFFu + ((u >> 16) & 1u)) >> 16;   // RNE
    return (unsigned short)r;
}

// packed fp32 FMA: acc += v * w (2 lanes of f32 each)
__device__ __forceinline__ void pkfma(f32x2& a, f32x2 v, f32x2 w) {
    asm("v_pk_fma_f32 %0, %1, %2, %0" : "+v"(a) : "v"(v), "v"(w));
}

// ---------------- weight prep: transpose + f32->bf16 ----------------
__global__ __launch_bounds__(256) void prep_weights(
    const float* __restrict__ W_off, const float* __restrict__ W_attn,
    const float* __restrict__ W_val, const float* __restrict__ W_out,
    unsigned short* __restrict__ WT_oa, unsigned short* __restrict__ WT_val,
    unsigned short* __restrict__ WT_out)
{
    const int gid = blockIdx.x * 256 + threadIdx.x;   // 896*256 total
    const int k = gid & 255;
    const int n = gid >> 8;
    if (n < 384) {
        const float v = (n < 256) ? W_off[k * 256 + n] : W_attn[k * 128 + (n - 256)];
        WT_oa[n * 256 + k] = f2bf(v);
    } else if (n < 640) {
        const int nn = n - 384;
        WT_val[nn * 256 + k] = f2bf(W_val[k * 256 + nn]);
    } else {
        const int nn = n - 640;
        WT_out[nn * 256 + k] = f2bf(W_out[k * 256 + nn]);
    }
}

// ---------------- merged V-proj + offset/attn-proj GEMM (NTW=2) ----------------
// grid = (5, NROW/64). x<2: V = bf16(value @ W_val + b_val) cols x*128..
//                      x>=2: OA = f32(query @ [W_off|W_attn] + bias) cols (x-2)*128..
__global__ __launch_bounds__(256, 5) void gemm_vo(
    const float* __restrict__ Aval, const float* __restrict__ Aqry,
    const unsigned short* __restrict__ Wval, const unsigned short* __restrict__ Woa,
    const float* __restrict__ bval, const float* __restrict__ boff,
    const float* __restrict__ battn,
    unsigned short* __restrict__ Vout, float* __restrict__ OAout)
{
    constexpr int NTW = 2;
    constexpr int NB  = 128;
    constexpr int K   = 256;
    __shared__ __align__(16) unsigned short As[64][40];
    __shared__ __align__(16) unsigned short Bs[NB][40];

    const int x    = blockIdx.x;
    const bool isV = (x < 2);
    const float* A = isV ? Aval : Aqry;
    const unsigned short* Wt = isV ? Wval : Woa;
    const int n0   = isV ? x * 128 : (x - 2) * 128;

    const int tid = threadIdx.x;
    const int m0 = blockIdx.y * 64;
    const int w  = tid >> 6;
    const int l  = tid & 63;
    const int lm = l & 15;
    const int lq = l >> 4;

    const int sr = tid >> 2;          // staging row 0..63
    const int kg = (tid & 3) * 8;     // staging k offset 0,8,16,24

    float4 pa0, pa1;                  // A prefetch regs
    short8 pb[NTW];                   // B prefetch regs

    auto gload = [&](int k0) {
        const float* ap = &A[(size_t)(m0 + sr) * K + k0 + kg];
        pa0 = *(const float4*)ap;
        pa1 = *(const float4*)(ap + 4);
        #pragma unroll
        for (int i = 0; i < NTW; ++i) {
            const int slot = tid + i * 256;
            const int n  = slot >> 2;
            const int kk = (slot & 3) * 8;
            pb[i] = *(const short8*)&Wt[(size_t)(n0 + n) * K + k0 + kk];
        }
    };

    f32x4 acc[4][NTW];
    #pragma unroll
    for (int rg = 0; rg < 4; ++rg)
        #pragma unroll
        for (int nt = 0; nt < NTW; ++nt)
            acc[rg][nt] = (f32x4){0.f, 0.f, 0.f, 0.f};

    gload(0);
    #pragma unroll 2
    for (int k0 = 0; k0 < K; k0 += 32) {
        uint4 pk;
        pk.x = (unsigned int)f2bf(pa0.x) | ((unsigned int)f2bf(pa0.y) << 16);
        pk.y = (unsigned int)f2bf(pa0.z) | ((unsigned int)f2bf(pa0.w) << 16);
        pk.z = (unsigned int)f2bf(pa1.x) | ((unsigned int)f2bf(pa1.y) << 16);
        pk.w = (unsigned int)f2bf(pa1.z) | ((unsigned int)f2bf(pa1.w) << 16);
        *(uint4*)&As[sr][kg] = pk;
        #pragma unroll
        for (int i = 0; i < NTW; ++i) {
            const int slot = tid + i * 256;
            const int n  = slot >> 2;
            const int kk = (slot & 3) * 8;
            *(short8*)&Bs[n][kk] = pb[i];
        }
        __syncthreads();

        if (k0 + 32 < K) gload(k0 + 32);   // issue next tile's loads now

        short8 af[4];
        #pragma unroll
        for (int rg = 0; rg < 4; ++rg)
            af[rg] = *(const short8*)&As[rg * 16 + lm][lq * 8];
        #pragma unroll
        for (int nt = 0; nt < NTW; ++nt) {
            const short8 bf = *(const short8*)&Bs[(w * NTW + nt) * 16 + lm][lq * 8];
            #pragma unroll
            for (int rg = 0; rg < 4; ++rg)
                acc[rg][nt] = __builtin_amdgcn_mfma_f32_16x16x32_bf16(af[rg], bf, acc[rg][nt], 0, 0, 0);
        }
        __syncthreads();
    }

    // ---- epilogue ----
    #pragma unroll
    for (int nt = 0; nt < NTW; ++nt) {
        const int col = n0 + (w * NTW + nt) * 16 + lm;
        float b;
        if (isV) b = bval[col];
        else     b = (col < 256) ? boff[col] : battn[col - 256];
        #pragma unroll
        for (int rg = 0; rg < 4; ++rg)
            #pragma unroll
            for (int r = 0; r < 4; ++r) {
                const int row = m0 + rg * 16 + lq * 4 + r;
                const float v = acc[rg][nt][r] + b;
                if (isV) Vout[(size_t)row * 256 + col] = f2bf(v);
                else     OAout[(size_t)row * 384 + col] = v;
            }
    }
}

// ---------------- bf16 MFMA GEMM (used for the final out-projection) ----------------
template <int NTW, bool A_BF16, bool OUT_BF16>
__global__ __launch_bounds__(256, 5) void gemm_mfma(
    const void* __restrict__ Av, const unsigned short* __restrict__ Wt,
    const float* __restrict__ bias0, const float* __restrict__ bias1, int nsplit,
    void* __restrict__ Cv, int N)
{
    constexpr int NB = NTW * 64;
    constexpr int K  = 256;
    __shared__ __align__(16) unsigned short As[64][40];
    __shared__ __align__(16) unsigned short Bs[NB][40];

    const int tid = threadIdx.x;
    const int m0 = blockIdx.y * 64;
    const int n0 = blockIdx.x * NB;
    const int w  = tid >> 6;
    const int l  = tid & 63;
    const int lm = l & 15;
    const int lq = l >> 4;

    const int sr = tid >> 2;
    const int kg = (tid & 3) * 8;

    float4 pa0, pa1; short8 pa_bf;
    short8 pb[NTW];

    auto gload = [&](int k0) {
        if (A_BF16) {
            const unsigned short* A = (const unsigned short*)Av;
            pa_bf = *(const short8*)&A[(size_t)(m0 + sr) * K + k0 + kg];
        } else {
            const float* A = (const float*)Av;
            const float* ap = &A[(size_t)(m0 + sr) * K + k0 + kg];
            pa0 = *(const float4*)ap;
            pa1 = *(const float4*)(ap + 4);
        }
        #pragma unroll
        for (int i = 0; i < NTW; ++i) {
            const int slot = tid + i * 256;
            const int n  = slot >> 2;
            const int kk = (slot & 3) * 8;
            pb[i] = *(const short8*)&Wt[(size_t)(n0 + n) * K + k0 + kk];
        }
    };

    f32x4 acc[4][NTW];
    #pragma unroll
    for (int rg = 0; rg < 4; ++rg)
        #pragma unroll
        for (int nt = 0; nt < NTW; ++nt)
            acc[rg][nt] = (f32x4){0.f, 0.f, 0.f, 0.f};

    gload(0);
    #pragma unroll 2
    for (int k0 = 0; k0 < K; k0 += 32) {
        if (A_BF16) {
            *(short8*)&As[sr][kg] = pa_bf;
        } else {
            uint4 pk;
            pk.x = (unsigned int)f2bf(pa0.x) | ((unsigned int)f2bf(pa0.y) << 16);
            pk.y = (unsigned int)f2bf(pa0.z) | ((unsigned int)f2bf(pa0.w) << 16);
            pk.z = (unsigned int)f2bf(pa1.x) | ((unsigned int)f2bf(pa1.y) << 16);
            pk.w = (unsigned int)f2bf(pa1.z) | ((unsigned int)f2bf(pa1.w) << 16);
            *(uint4*)&As[sr][kg] = pk;
        }
        #pragma unroll
        for (int i = 0; i < NTW; ++i) {
            const int slot = tid + i * 256;
            const int n  = slot >> 2;
            const int kk = (slot & 3) * 8;
            *(short8*)&Bs[n][kk] = pb[i];
        }
        __syncthreads();

        if (k0 + 32 < K) gload(k0 + 32);

        short8 af[4];
        #pragma unroll
        for (int rg = 0; rg < 4; ++rg)
            af[rg] = *(const short8*)&As[rg * 16 + lm][lq * 8];
        #pragma unroll
        for (int nt = 0; nt < NTW; ++nt) {
            const short8 bf = *(const short8*)&Bs[(w * NTW + nt) * 16 + lm][lq * 8];
            #pragma unroll
            for (int rg = 0; rg < 4; ++rg)
                acc[rg][nt] = __builtin_amdgcn_mfma_f32_16x16x32_bf16(af[rg], bf, acc[rg][nt], 0, 0, 0);
        }
        __syncthreads();
    }

    #pragma unroll
    for (int nt = 0; nt < NTW; ++nt) {
        const int col = n0 + (w * NTW + nt) * 16 + lm;
        const float b = (col < nsplit) ? bias0[col] : bias1[col - nsplit];
        #pragma unroll
        for (int rg = 0; rg < 4; ++rg)
            #pragma unroll
            for (int r = 0; r < 4; ++r) {
                const int row = m0 + rg * 16 + lq * 4 + r;
                const float v = acc[rg][nt][r] + b;
                if (OUT_BF16) ((unsigned short*)Cv)[(size_t)row * N + col] = f2bf(v);
                else          ((float*)Cv)[(size_t)row * N + col] = v;
            }
    }
}

// ---------------- bilinear sampling v4 ----------------
// Block = 256 threads = 4 waves, 4 CONSECUTIVE rows (one per wave).
// XCD batch-affinity swizzle: blocks dispatch round-robin over 8 XCDs; map
//   xcd pair {2b,2b+1} -> batch b so each XCD's L2 only holds one batch's V
//   (6.3 MB working set vs 25 MB without affinity).
// Phase 1: coalesced float4 stage of the 4 OA rows into LDS (pr_o area),
//   softmax scratch in pr_w area, per-thread 2 samples -> corner offsets +
//   aw-premultiplied corner weights computed into regs, sync, store pr_o/pr_w.
// Phase 2: per-wave j-loop over 8 samples with explicit lookahead:
//   ds_read offsets/weights 2 steps ahead, global V loads 1 step ahead.
//   ~78 live VGPRs; __launch_bounds__(256,6) caps at ~84 (no spill).
// Phase 3: fold corner-pair partials, cross-half shfl reduce, bf16 write.
__global__ __launch_bounds__(256, 6) void sample_kernel(
    const unsigned short* __restrict__ V,   // bf16 [b, pix, 256]
    const float* __restrict__ OA,           // [row][384]: raw offsets + logits
    const float* __restrict__ refp,         // [row][4][2]
    unsigned short* __restrict__ ACC)       // bf16 [row][256]
{
    __shared__ __align__(16) unsigned int pr_o[512][4];   // 8 KB offsets (stage buf first)
    __shared__ __align__(16) unsigned int pr_w[512][4];   // 8 KB weights (scratch first)

    const int tid = threadIdx.x;

    // ---- XCD batch-affinity swizzle (12240 blocks = 8 XCD x 1530) ----
    const unsigned bx = blockIdx.x;
    const int xcd  = bx & 7;
    const int slot = bx >> 3;
    const int batch = xcd >> 1;
    const int wb   = slot * 2 + (xcd & 1);        // 0..3059 within batch
    const int row0 = batch * LQ + wb * 4;

    // ---- phase 1: stage OA, softmax, coords, corner prep ----
    {
        // coalesced stage: 4 rows x 384 f32 = 384 float4
        float4* dst = (float4*)pr_o;
        const float4* src = (const float4*)(OA + (size_t)row0 * 384);
        dst[tid] = src[tid];
        if (tid < 128) dst[tid + 256] = src[tid + 256];
        __syncthreads();

        const int g = tid & 31;            // r*8 + h
        const int r = g >> 3;
        const int h = g & 7;
        const int L = tid >> 5;            // 0..7
        const float* rowp = (const float*)pr_o + r * 384;

        const float lg0 = rowp[256 + h * 16 + L];
        const float lg1 = rowp[256 + h * 16 + L + 8];

        float* smax = (float*)pr_w;        // [8][33] scratch
        float* ssum = smax + 264;
        smax[L * 33 + g] = fmaxf(lg0, lg1);
        __syncthreads();
        float m = smax[g];
        #pragma unroll
        for (int k = 1; k < 8; ++k) m = fmaxf(m, smax[k * 33 + g]);
        const float e0 = __expf(lg0 - m);
        const float e1 = __expf(lg1 - m);
        ssum[L * 33 + g] = e0 + e1;
        __syncthreads();
        float sden = ssum[g];
        #pragma unroll
        for (int k = 1; k < 8; ++k) sden += ssum[k * 33 + g];
        const float inv = 1.0f / sden;

        uint4 ostash[2], wstash[2];
        int   sidx[2];
        #pragma unroll
        for (int ss = 0; ss < 2; ++ss) {
            const int lp  = L + ss * 8;
            const int s   = lp * 32 + g;
            const int lvl = lp >> 2;
            const int Wl = LVL_W[lvl], Hl = LVL_H[lvl], st = LVL_ST[lvl];

            const float2 oxy = *(const float2*)&rowp[h * 32 + lp * 2];
            const float2 rxy = *(const float2*)&refp[(size_t)(row0 + r) * 8 + lvl * 2];
            const float wgt = (ss ? e1 : e0) * inv;

            // mimic reference op order: lx = rx + ox/Wl; gx = lx*Wl - 0.5
            const float gx = (rxy.x + oxy.x / (float)Wl) * (float)Wl - 0.5f;
            const float gy = (rxy.y + oxy.y / (float)Hl) * (float)Hl - 0.5f;

            const float fx = floorf(gx), fy = floorf(gy);
            const float wx = gx - fx,    wy = gy - fy;
            const int x0 = (int)fx, y0 = (int)fy;
            const int x1 = x0 + 1,  y1 = y0 + 1;

            const bool bx0 = ((unsigned)x0 < (unsigned)Wl);
            const bool bx1 = ((unsigned)x1 < (unsigned)Wl);
            const bool by0 = ((unsigned)y0 < (unsigned)Hl);
            const bool by1 = ((unsigned)y1 < (unsigned)Hl);
            const float w00 = (bx0 && by0) ? (1.f - wx) * (1.f - wy) * wgt : 0.f;
            const float w10 = (bx1 && by0) ? wx * (1.f - wy) * wgt : 0.f;
            const float w01 = (bx0 && by1) ? (1.f - wx) * wy * wgt : 0.f;
            const float w11 = (bx1 && by1) ? wx * wy * wgt : 0.f;

            const int cx0 = min(max(x0, 0), Wl - 1);
            const int cx1 = min(max(x1, 0), Wl - 1);
            const int cy0 = min(max(y0, 0), Hl - 1);
            const int cy1 = min(max(y1, 0), Hl - 1);

            uint4 o;
            o.x = (unsigned int)(st + cy0 * Wl + cx0) * 512u;   // pix * 256ch * 2B
            o.y = (unsigned int)(st + cy0 * Wl + cx1) * 512u;
            o.z = (unsigned int)(st + cy1 * Wl + cx0) * 512u;
            o.w = (unsigned int)(st + cy1 * Wl + cx1) * 512u;
            ostash[ss] = o;

            uint4 wv;
            wv.x = __float_as_uint(w00); wv.y = __float_as_uint(w10);
            wv.z = __float_as_uint(w01); wv.w = __float_as_uint(w11);
            wstash[ss] = wv;
            sidx[ss] = s;
        }
        __syncthreads();                   // all oas/scratch reads done
        *(uint4*)&pr_o[sidx[0]][0] = ostash[0];
        *(uint4*)&pr_o[sidx[1]][0] = ostash[1];
        *(uint4*)&pr_w[sidx[0]][0] = wstash[0];
        *(uint4*)&pr_w[sidx[1]][0] = wstash[1];
    }
    __syncthreads();

    // ---- phase 2: sampling main loop (lookahead pipeline) ----
    const int w    = tid >> 6;             // wave = row within block
    const int l    = tid & 63;
    const int half = l >> 5;               // lp group (0-7 vs 8-15)
    const int head = (l >> 2) & 7;
    const int c16  = (l & 3) * 16;

    const int row  = __builtin_amdgcn_readfirstlane(row0 + w);
    const char* vrow = (const char*)V + (size_t)batch * ((size_t)LQ * 512);
    const unsigned int lane_byte = (unsigned int)(head * 64 + c16);
    const int sid0 = half * 256 + w * 8 + head;   // + j*32 per lp step

    uint4 ofs[2];
    f32x4 wv[2];
    uint4 dat[2][4];
    f32x2 accA[4], accB[4];
    #pragma unroll
    for (int i = 0; i < 4; ++i) { accA[i] = (f32x2){0.f,0.f}; accB[i] = (f32x2){0.f,0.f}; }

    auto ldglb = [&](int buf) {
        const uint4 o = ofs[buf];
        dat[buf][0] = *(const uint4*)(vrow + (lane_byte + o.x));
        dat[buf][1] = *(const uint4*)(vrow + (lane_byte + o.y));
        dat[buf][2] = *(const uint4*)(vrow + (lane_byte + o.z));
        dat[buf][3] = *(const uint4*)(vrow + (lane_byte + o.w));
    };
    auto ldpr = [&](int j, int buf) {
        ofs[buf] = *(const uint4*)&pr_o[sid0 + j * 32][0];
        wv[buf]  = *(const f32x4*)&pr_w[sid0 + j * 32][0];
    };
    auto pkstep = [&](f32x2& A, f32x2& B, unsigned u0, unsigned u1, f32x2 w2) {
        f32x2 pa, pb;
        pa.x = __uint_as_float(u0 << 16);
        pa.y = __uint_as_float(u1 << 16);
        pb.x = __uint_as_float(u0 & 0xffff0000u);
        pb.y = __uint_as_float(u1 & 0xffff0000u);
        pkfma(A, pa, w2);
        pkfma(B, pb, w2);
    };
    auto consume = [&](int buf) {
        f32x2 w01; w01.x = wv[buf].x; w01.y = wv[buf].y;
        f32x2 w23; w23.x = wv[buf].z; w23.y = wv[buf].w;
        const uint4 d0 = dat[buf][0], d1 = dat[buf][1];
        pkstep(accA[0], accB[0], d0.x, d1.x, w01);
        pkstep(accA[1], accB[1], d0.y, d1.y, w01);
        pkstep(accA[2], accB[2], d0.z, d1.z, w01);
        pkstep(accA[3], accB[3], d0.w, d1.w, w01);
        const uint4 d2 = dat[buf][2], d3 = dat[buf][3];
        pkstep(accA[0], accB[0], d2.x, d3.x, w23);
        pkstep(accA[1], accB[1], d2.y, d3.y, w23);
        pkstep(accA[2], accB[2], d2.z, d3.z, w23);
        pkstep(accA[3], accB[3], d2.w, d3.w, w23);
    };

    // prologue: offsets/weights for j=0,1 ; V-loads for j=0
    ldpr(0, 0);
    ldpr(1, 1);
    ldglb(0);
    #pragma unroll
    for (int j = 0; j < 8; ++j) {
        if (j + 1 < 8) ldglb((j + 1) & 1);       // V loads 1 step ahead
        consume(j & 1);
        if (j + 2 < 8) ldpr(j + 2, j & 1);       // LDS reads 2 steps ahead
    }

    // ---- phase 3: fold corner partials, cross-half reduce, write ----
    float c[8];
    #pragma unroll
    for (int i = 0; i < 4; ++i) {
        c[2 * i]     = accA[i].x + accA[i].y;
        c[2 * i + 1] = accB[i].x + accB[i].y;
    }
    #pragma unroll
    for (int i = 0; i < 8; ++i) c[i] += __shfl_xor(c[i], 32);

    if (half == 0) {
        uint4 o;
        o.x = (unsigned int)f2bf(c[0]) | ((unsigned int)f2bf(c[1]) << 16);
        o.y = (unsigned int)f2bf(c[2]) | ((unsigned int)f2bf(c[3]) << 16);
        o.z = (unsigned int)f2bf(c[4]) | ((unsigned int)f2bf(c[5]) << 16);
        o.w = (unsigned int)f2bf(c[6]) | ((unsigned int)f2bf(c[7]) << 16);
        *(uint4*)((char*)(ACC + (size_t)row * EMBED) + head * 64 + c16) = o;
    }
}

// ---------------- launch ----------------
extern "C" void kernel_launch(void* const* d_in, const int* in_sizes, int n_in,
                              void* d_out, int out_size, void* d_ws, size_t ws_size,
                              hipStream_t stream) {
    const float* query  = (const float*)d_in[0];
    const float* refp   = (const float*)d_in[1];
    const float* value  = (const float*)d_in[2];
    // d_in[3] = value_spatial_shapes (static, hard-coded)
    const float* W_off  = (const float*)d_in[4];
    const float* b_off  = (const float*)d_in[5];
    const float* W_attn = (const float*)d_in[6];
    const float* b_attn = (const float*)d_in[7];
    const float* W_val  = (const float*)d_in[8];
    const float* b_val  = (const float*)d_in[9];
    const float* W_out  = (const float*)d_in[10];
    const float* b_out  = (const float*)d_in[11];
    float* out = (float*)d_out;

    // ---- workspace layout ----
    unsigned short* WT_oa  = (unsigned short*)d_ws;          // [384][256] bf16
    unsigned short* WT_val = WT_oa  + 384 * 256;             // [256][256] bf16
    unsigned short* WT_out = WT_val + 256 * 256;             // [256][256] bf16
    unsigned short* V      = WT_out + 256 * 256;             // [NROW][256] bf16
    float*          OA     = (float*)(V + (size_t)NROW * EMBED);        // [NROW][384] f32
    unsigned short* ACCb   = (unsigned short*)(OA + (size_t)NROW * 384); // [NROW][256] bf16

    dim3 blk(256);

    // 0. weight transpose + convert
    prep_weights<<<896, blk, 0, stream>>>(W_off, W_attn, W_val, W_out,
                                          WT_oa, WT_val, WT_out);
    // 1+2 merged. V = bf16(value@W_val+b_val); OA = query@[W_off|W_attn]+bias
    gemm_vo<<<dim3(5, NROW / 64), blk, 0, stream>>>(
        value, query, WT_val, WT_oa, b_val, b_off, b_attn, V, OA);
    // 3. deformable sampling (softmax+coords fused) -> bf16 ACC
    sample_kernel<<<NROW / 4, blk, 0, stream>>>(V, OA, refp, ACCb);
    // 4. out = ACC @ W_out + b_out
    gemm_mfma<2, true, false><<<dim3(2, NROW / 64), blk, 0, stream>>>(
        ACCb, WT_out, b_out, b_out, 256, out, 256);
}